// Round 10
// baseline (350.474 us; speedup 1.0000x reference)
//
#include <hip/hip_runtime.h>

#define BB 64
#define TT 512
#define NN 48
#define PP 16

typedef float f4 __attribute__((ext_vector_type(4)));
typedef short s8v __attribute__((ext_vector_type(8)));
typedef int i4v __attribute__((ext_vector_type(4)));

#define LN2 0.6931471805599453f

__device__ __forceinline__ unsigned f2bf_bits(float x) {
    unsigned u = __builtin_bit_cast(unsigned, x);
    return (u + 0x7fffu + ((u >> 16) & 1u)) >> 16;
}
__device__ __forceinline__ int pk_bf16(float a, float b) {
    return (int)(f2bf_bits(a) | (f2bf_bits(b) << 16));
}
__device__ __forceinline__ float wsum(float v) {
#pragma unroll
    for (int k = 32; k >= 1; k >>= 1) v += __shfl_xor(v, k, 64);
    return v;
}

#define MFMA(A_, B_, C_) __builtin_amdgcn_mfma_f32_16x16x32_bf16(A_, B_, C_, 0, 0, 0)

// global -> LDS direct DMA, 16B per lane. LDS dst is wave-uniform base + lane*16.
__device__ __forceinline__ void gl_lds16(const void* g, void* l) {
    __builtin_amdgcn_global_load_lds(
        (const __attribute__((address_space(1))) unsigned int*)g,
        (__attribute__((address_space(3))) unsigned int*)l, 16, 0, 0);
}
// s_waitcnt imm: vmcnt[3:0]|expcnt[6:4]|lgkmcnt[11:8]|vmcnt[5:4]<<14
#define WAIT_VM48() __builtin_amdgcn_s_waitcnt(0xCF70)
#define WAIT_VM0() __builtin_amdgcn_s_waitcnt(0x0F70)

#define RESCALE(CNT)                                                         \
    do {                                                                     \
        float Sx = ((D0[0] + D0[1]) + (D0[2] + D0[3])) +                     \
                   ((D1[0] + D1[1]) + (D1[2] + D1[3])) +                     \
                   ((D2[0] + D2[1]) + (D2[2] + D2[3]));                      \
        Sx += __shfl_xor(Sx, 16, 64);                                        \
        Sx += __shfl_xor(Sx, 32, 64);                                        \
        int e_ = (__builtin_bit_cast(int, Sx) >> 23) - 127;                  \
        float scl_ = __builtin_bit_cast(float, (127 - e_) << 23);            \
        CNT += e_;                                                           \
        D0 *= scl_; D1 *= scl_; D2 *= scl_;                                  \
    } while (0)

#define EMMUL(E0, E1, E2)                                                    \
    do {                                                                     \
        D0[0] *= __expf(E0.x); D0[1] *= __expf(E0.y);                        \
        D0[2] *= __expf(E0.z); D0[3] *= __expf(E0.w);                        \
        D1[0] *= __expf(E1.x); D1[1] *= __expf(E1.y);                        \
        D1[2] *= __expf(E1.z); D1[3] *= __expf(E1.w);                        \
        D2[0] *= __expf(E2.x); D2[1] *= __expf(E2.y);                        \
        D2[2] *= __expf(E2.z); D2[3] *= __expf(E2.w);                        \
    } while (0)

#define REPACK_B()                                                           \
    do {                                                                     \
        i4v nb0 = {pk_bf16(D0[0], D0[1]), pk_bf16(D0[2], D0[3]),             \
                   pk_bf16(D1[0], D1[1]), pk_bf16(D1[2], D1[3])};            \
        i4v nb1 = {pk_bf16(D2[0], D2[1]), pk_bf16(D2[2], D2[3]), 0, 0};      \
        B0 = __builtin_bit_cast(s8v, nb0);                                   \
        B1 = __builtin_bit_cast(s8v, nb1);                                   \
    } while (0)

#define DO_MFMA6()                                                           \
    do {                                                                     \
        D0 = MFMA(A[0][1], B1, Z); D0 = MFMA(A[0][0], B0, D0);               \
        D1 = MFMA(A[1][1], B1, Z); D1 = MFMA(A[1][0], B0, D1);               \
        D2 = MFMA(A[2][1], B1, Z); D2 = MFMA(A[2][0], B0, D2);               \
    } while (0)

// Forward chain with VGPR prefetch ring (used by L/R, steps<=15).
template <int RP, int DEPTH>
__device__ __forceinline__ void fwd_chain(const float* __restrict__ p0, int estride,
                                          int steps, const s8v (&A)[3][2],
                                          f4& D0, f4& D1, f4& D2, int& Cexp) {
    const f4 Z = {0.f, 0.f, 0.f, 0.f};
    float4 ua = *(const float4*)(p0);
    float4 ub = *(const float4*)(p0 + 16);
    float4 uc = *(const float4*)(p0 + 32);
    i4v b0i = {pk_bf16(__expf(ua.x), __expf(ua.y)), pk_bf16(__expf(ua.z), __expf(ua.w)),
               pk_bf16(__expf(ub.x), __expf(ub.y)), pk_bf16(__expf(ub.z), __expf(ub.w))};
    i4v b1i = {pk_bf16(__expf(uc.x), __expf(uc.y)), pk_bf16(__expf(uc.z), __expf(uc.w)), 0, 0};
    s8v B0 = __builtin_bit_cast(s8v, b0i);
    s8v B1 = __builtin_bit_cast(s8v, b1i);

    float4 r[DEPTH][3];
    auto emload = [&](int d, int S) {
        int cl = S < steps ? S : steps;
        const float* q = p0 + (size_t)cl * (size_t)estride;
        r[d][0] = *(const float4*)q;
        r[d][1] = *(const float4*)(q + 16);
        r[d][2] = *(const float4*)(q + 32);
    };
#pragma unroll
    for (int d = 0; d < DEPTH; ++d) emload(d, 1 + d);

    int s = 1;
    for (;;) {
#pragma unroll
        for (int d = 0; d < DEPTH; ++d) {
            DO_MFMA6();
            EMMUL(r[d][0], r[d][1], r[d][2]);
            if (s == steps) return;
            if ((s & (RP - 1)) == 0) RESCALE(Cexp);
            REPACK_B();
            emload(d, s + DEPTH);
            ++s;
        }
    }
}

template <int RP, int DEPTH>
__device__ __forceinline__ float den16(const float* __restrict__ p0, int estride,
                                       int steps, const s8v (&A)[3][2]) {
    f4 D0, D1, D2;
    int Cexp = 0;
    fwd_chain<RP, DEPTH>(p0, estride, steps, A, D0, D1, D2, Cexp);
    float S = ((D0[0] + D0[1]) + (D0[2] + D0[3])) +
              ((D1[0] + D1[1]) + (D1[2] + D1[3])) +
              ((D2[0] + D2[1]) + (D2[2] + D2[3]));
    S += __shfl_xor(S, 16, 64);
    S += __shfl_xor(S, 32, 64);
    return __logf(S) + (float)Cexp * LN2;
}

__device__ __forceinline__ float den0(const float* __restrict__ p0) {
    float4 ua = *(const float4*)(p0);
    float4 ub = *(const float4*)(p0 + 16);
    float4 uc = *(const float4*)(p0 + 32);
    float S = (__expf(ua.x) + __expf(ua.y) + __expf(ua.z) + __expf(ua.w)) +
              (__expf(ub.x) + __expf(ub.y) + __expf(ub.z) + __expf(ub.w)) +
              (__expf(uc.x) + __expf(uc.y) + __expf(uc.z) + __expf(uc.w));
    S += __shfl_xor(S, 16, 64);
    S += __shfl_xor(S, 32, 64);
    return __logf(S);
}

// A-frags fwd: A[m][k] = exp(trans[σ(k)][t*16+m])  (Eᵀ·u)
__device__ __forceinline__ void build_A_fwd(const float* __restrict__ st, s8v (&A)[3][2]) {
    int lane = threadIdx.x & 63, m = lane & 15, quad = lane >> 4;
#pragma unroll
    for (int t = 0; t < 3; ++t) {
        int col = t * 16 + m;
        i4v v0 = {pk_bf16(__expf(st[(quad * 4 + 0) * NN + col]), __expf(st[(quad * 4 + 1) * NN + col])),
                  pk_bf16(__expf(st[(quad * 4 + 2) * NN + col]), __expf(st[(quad * 4 + 3) * NN + col])),
                  pk_bf16(__expf(st[(16 + quad * 4 + 0) * NN + col]), __expf(st[(16 + quad * 4 + 1) * NN + col])),
                  pk_bf16(__expf(st[(16 + quad * 4 + 2) * NN + col]), __expf(st[(16 + quad * 4 + 3) * NN + col]))};
        i4v v1 = {pk_bf16(__expf(st[(32 + quad * 4 + 0) * NN + col]), __expf(st[(32 + quad * 4 + 1) * NN + col])),
                  pk_bf16(__expf(st[(32 + quad * 4 + 2) * NN + col]), __expf(st[(32 + quad * 4 + 3) * NN + col])),
                  0, 0};
        A[t][0] = __builtin_bit_cast(s8v, v0);
        A[t][1] = __builtin_bit_cast(s8v, v1);
    }
}

// A-frags bwd: A[m][k] = exp(trans[t*16+m][σ(k)])  (E·x)
__device__ __forceinline__ void build_A_bwd(const float* __restrict__ st, s8v (&A)[3][2]) {
    int lane = threadIdx.x & 63, m = lane & 15, quad = lane >> 4;
#pragma unroll
    for (int t = 0; t < 3; ++t) {
        const float* row = st + (t * 16 + m) * NN;
        i4v v0 = {pk_bf16(__expf(row[quad * 4 + 0]), __expf(row[quad * 4 + 1])),
                  pk_bf16(__expf(row[quad * 4 + 2]), __expf(row[quad * 4 + 3])),
                  pk_bf16(__expf(row[16 + quad * 4 + 0]), __expf(row[16 + quad * 4 + 1])),
                  pk_bf16(__expf(row[16 + quad * 4 + 2]), __expf(row[16 + quad * 4 + 3]))};
        i4v v1 = {pk_bf16(__expf(row[32 + quad * 4 + 0]), __expf(row[32 + quad * 4 + 1])),
                  pk_bf16(__expf(row[32 + quad * 4 + 2]), __expf(row[32 + quad * 4 + 3])),
                  0, 0};
        A[t][0] = __builtin_bit_cast(s8v, v0);
        A[t][1] = __builtin_bit_cast(s8v, v1);
    }
}

__device__ __forceinline__ void dumpD(float* __restrict__ dst, int* __restrict__ cdst,
                                      int g, f4 D0, f4 D1, f4 D2, int Cexp) {
    int lane = threadIdx.x & 63, seq = lane & 15, quad = lane >> 4;
    float* b = dst + (size_t)(g * 16 + seq) * 48 + quad * 4;
#pragma unroll
    for (int r = 0; r < 4; ++r) {
        b[0 * 16 + r] = D0[r];
        b[1 * 16 + r] = D1[r];
        b[2 * 16 + r] = D2[r];
    }
    if (quad == 0) cdst[g * 16 + seq] = Cexp;
}

__global__ void zero_out(float* out) {
    if (threadIdx.x < 3) out[threadIdx.x] = 0.f;
}

#define WS_BETA (64 * 16 * 48)
#define WS_C (2 * 64 * 16 * 48)

// ---------------------------------------------------------------------------
// crf_T: LDS-staged DMA pipeline. 128 blocks x 64 thr (1 wave). bid<64: fwd
// half (g=bid), else bwd half. Stage = 16 steps x 16 seqs x 192B = 48KB,
// double buffered, filled by explicit global_load_lds (can't be sunk by the
// register allocator), drained with s_waitcnt vmcnt(48) (stage q landed while
// stage q+1 is in flight).
// ---------------------------------------------------------------------------
#define SEQ_STRIDE 3088  // 16*192 + 16B pad: word stride 772 ≡ 4 mod 32 → 2-way banks (free)
__global__ __launch_bounds__(64, 1) void crf_T(const float* __restrict__ logits,
                                               const float* __restrict__ transT,
                                               float* __restrict__ ws) {
    __shared__ float st[NN * NN];
    __shared__ __align__(16) char ebuf[2][16 * SEQ_STRIDE];
    const int tid = threadIdx.x, bid = blockIdx.x;
    for (int i = tid; i < NN * NN; i += 64) st[i] = transT[i];
    __syncthreads();

    const int lane = tid & 63, seq = lane & 15, quad = lane >> 4;
    const int dir = bid >> 6, g = bid & 63;
    const int p = g >> 2, b0 = (g & 3) * 16;
    const int steps = (TT - 1) - p;
    const int m = steps >> 1, nb = steps - m;
    const int nsteps = (dir == 0) ? m : nb;
    const int hi = steps;
    const int nst = (nsteps + 15) >> 4;

    s8v A[3][2];
    if (dir == 0) build_A_fwd(st, A);
    else build_A_bwd(st, A);

    auto issue = [&](int q) {
        if (q >= nst) return;
        int base_row = (dir == 0) ? (1 + q * 16) : (hi - q * 16 - 15);
        char* lb = (char*)ebuf[q & 1];
        const char* gl = (const char*)logits + lane * 16;
#pragma unroll 4
        for (int s2 = 0; s2 < 16; ++s2) {
            const char* gc = gl + ((size_t)(p * BB + b0 + s2) * (TT * NN) +
                                   (size_t)base_row * NN) * 4;
            gl_lds16(gc, lb + s2 * SEQ_STRIDE);
            gl_lds16(gc + 1024, lb + s2 * SEQ_STRIDE + 1024);
            gl_lds16(gc + 2048, lb + s2 * SEQ_STRIDE + 2048);
        }
    };

    const f4 Z = {0.f, 0.f, 0.f, 0.f};
    f4 D0 = Z, D1 = Z, D2 = Z;
    s8v B0, B1;
    int Cexp = 0;
    if (dir == 0) {
        const float* p0 = logits + (size_t)(p * BB + b0 + seq) * (TT * NN) + quad * 4;
        float4 ua = *(const float4*)(p0);
        float4 ub = *(const float4*)(p0 + 16);
        float4 uc = *(const float4*)(p0 + 32);
        i4v b0i = {pk_bf16(__expf(ua.x), __expf(ua.y)), pk_bf16(__expf(ua.z), __expf(ua.w)),
                   pk_bf16(__expf(ub.x), __expf(ub.y)), pk_bf16(__expf(ub.z), __expf(ub.w))};
        i4v b1i = {pk_bf16(__expf(uc.x), __expf(uc.y)), pk_bf16(__expf(uc.z), __expf(uc.w)), 0, 0};
        B0 = __builtin_bit_cast(s8v, b0i);
        B1 = __builtin_bit_cast(s8v, b1i);
    } else {
        D0 = f4{1.f, 1.f, 1.f, 1.f}; D1 = D0; D2 = D0;
    }

    issue(0);
    issue(1);
    for (int q = 0; q < nst; ++q) {
        if (q + 2 <= nst) WAIT_VM48();
        else WAIT_VM0();
        __builtin_amdgcn_sched_barrier(0);
        const char* lb = (const char*)ebuf[q & 1] + seq * SEQ_STRIDE + quad * 16;
        int cnt = nsteps - q * 16;
        if (cnt > 16) cnt = 16;
        for (int t2 = 0; t2 < cnt; ++t2) {
            int j = q * 16 + t2;
            int lr = (dir == 0) ? t2 : (15 - t2);
            const char* lrow = lb + lr * 192;
            float4 e0 = *(const float4*)(lrow);
            float4 e1 = *(const float4*)(lrow + 64);
            float4 e2 = *(const float4*)(lrow + 128);
            if (dir == 0) {
                DO_MFMA6();
                EMMUL(e0, e1, e2);
                if (j < nsteps - 1) {
                    if (((j + 1) & 3) == 0) RESCALE(Cexp);
                    REPACK_B();
                }
            } else {
                EMMUL(e0, e1, e2);
                REPACK_B();
                DO_MFMA6();
                if (j < nsteps - 1 && ((j + 1) & 3) == 0) RESCALE(Cexp);
            }
        }
        issue(q + 2);
    }

    int* cf = (int*)(ws + WS_C);
    if (dir == 0) dumpD(ws, cf, g, D0, D1, D2, Cexp);
    else dumpD(ws + WS_BETA, cf + 1024, g, D0, D1, D2, Cexp);
}

// ---------------------------------------------------------------------------
// crf_LR: 4352 blocks x 64 thr (1 wave each), one role per block:
//  bid<1984          : L uniform — wave=(b, t0=16*tb), seqs = t 0..15 of block;
//                      step chunks are CONTIGUOUS 3KB (16 t-rows adjacent).
//  bid<3968          : R uniform — same with t0=16+16*tb (diagonal stride).
//  bid<4032          : L tail (t=496..511, old b-grouping).
//  bid<4096          : R tail (t=0..15, old b-grouping).
//  bid<4352          : T numerator.
// ---------------------------------------------------------------------------
__global__ __launch_bounds__(64, 3) void crf_LR(const float* __restrict__ logits,
                                                const float* __restrict__ transT,
                                                const float* __restrict__ transL,
                                                const float* __restrict__ transR,
                                                const int* __restrict__ tags,
                                                float* __restrict__ out) {
    __shared__ float st[NN * NN];
    const int tid = threadIdx.x, bid = blockIdx.x;
    const int lane = tid & 63;
    const int quad = lane >> 4, seq = lane & 15;
    const int SPN = BB * TT * NN;

    const float* tr;
    if (bid < 1984) tr = transL;
    else if (bid < 3968) tr = transR;
    else if (bid < 4032) tr = transL;
    else if (bid < 4096) tr = transR;
    else tr = transT;
    for (int i = tid; i < NN * NN; i += 64) st[i] = tr[i];
    __syncthreads();

    float contrib = 0.f;
    int oi;
    if (bid < 3968) {
        // ---- uniform L/R: 16 steps, contiguous per-step chunks
        const int isL = bid < 1984;
        const int i = isL ? bid : bid - 1984;
        const int tb = i >> 6, b = i & 63;
        const int t0 = (isL ? 0 : 16) + tb * 16;
        oi = isL ? 1 : 2;
        const int estride = isL ? SPN : SPN - NN;
        s8v A[3][2];
        build_A_fwd(st, A);
        const float* p0 = logits + (size_t)(b * TT + t0 + seq) * NN + quad * 4;
        float ld = den16<8, 6>(p0, estride, PP - 1, A);
        // numerator (16 seqs x 4 p-phases)
        int sq = lane >> 2, pc = lane & 3;
        int tq = t0 + sq;
        float sc = 0.f;
        if (isL) {
            for (int p2 = pc; p2 < PP; p2 += 4) {
                int ix = (p2 * BB + b) * TT + tq;
                int tg = tags[ix];
                sc += logits[(size_t)ix * NN + tg];
                if (p2 >= 1) sc += st[tags[ix - BB * TT] * NN + tg];
            }
        } else {
            for (int p2 = pc; p2 < PP; p2 += 4) {
                int ix = (p2 * BB + b) * TT + (tq - p2);
                int tg = tags[ix];
                sc += logits[(size_t)ix * NN + tg];
                if (p2 >= 1) sc += st[tags[ix - BB * TT + 1] * NN + tg];
            }
        }
        contrib = ((quad == 0) ? ld : 0.f) - sc;
    } else if (bid < 4096) {
        // ---- tails: old b-grouping, fixed t, 16 b-seqs per wave
        const int isL = bid < 4032;
        const int i = isL ? bid - 3968 : bid - 4032;
        const int t = isL ? 496 + (i >> 2) : (i >> 2);
        const int b0 = (i & 3) * 16;
        oi = isL ? 1 : 2;
        const int Lh = isL ? (TT - t) : (t + 1);
        const int steps = Lh - 1;
        const int estride = isL ? SPN : SPN - NN;
        s8v A[3][2];
        build_A_fwd(st, A);
        const float* p0 = logits + (size_t)(b0 + seq) * (TT * NN) + t * NN + quad * 4;
        float ld = (steps > 0) ? den16<8, 6>(p0, estride, steps, A) : den0(p0);
        float sc = 0.f;
        int sq = lane >> 2, pc = lane & 3;
        int bq = b0 + sq;
        if (isL) {
            for (int p2 = pc; p2 < Lh; p2 += 4) {
                int ix = (p2 * BB + bq) * TT + t;
                int tg = tags[ix];
                sc += logits[(size_t)ix * NN + tg];
                if (p2 >= 1) sc += st[tags[ix - BB * TT] * NN + tg];
            }
        } else {
            for (int p2 = pc; p2 < Lh; p2 += 4) {
                int ix = (p2 * BB + bq) * TT + (t - p2);
                int tg = tags[ix];
                sc += logits[(size_t)ix * NN + tg];
                if (p2 >= 1) sc += st[tags[ix - BB * TT + 1] * NN + tg];
            }
        }
        contrib = ((quad == 0) ? ld : 0.f) - sc;
    } else {
        // ---- T numerator: q = bid-4096: g = q>>2, phase = q&3
        oi = 0;
        int q = bid - 4096;
        int g = q >> 2, phase = q & 3;
        int p = g >> 2, b0 = (g & 3) * 16;
        int Ls = TT - p;
        int sq = lane >> 2;
        int t0 = phase * 4 + (lane & 3);
        const float* lgs = logits + (size_t)(p * BB + b0 + sq) * (TT * NN);
        const int* tgs = tags + (size_t)(p * BB + b0 + sq) * TT;
        float sc = 0.f;
        for (int t = t0; t < Ls; t += 16) {
            int tg = tgs[t];
            float e = lgs[t * NN + tg];
            float tsc = (t >= 1) ? st[tgs[t - 1] * NN + tg] : 0.f;
            sc += e + tsc;
        }
        contrib = -sc;
    }

    contrib = wsum(contrib);
    if (lane == 0) atomicAdd(&out[oi], contrib);
}

// Combine T halves: out[0] += Σ_idx [ log(Σ_s alpha*beta) + ln2*(cf+cb) ]
__global__ __launch_bounds__(256) void t_combine(const float* __restrict__ ws,
                                                 float* __restrict__ out) {
    const int idx = blockIdx.x * 256 + threadIdx.x;  // 0..1023
    const float* ap = ws + (size_t)idx * 48;
    const float* bp = ws + WS_BETA + (size_t)idx * 48;
    const int* cf = (const int*)(ws + WS_C);
    const int* cb = cf + 1024;
    float Zv = 0.f;
#pragma unroll
    for (int s = 0; s < 48; ++s) Zv += ap[s] * bp[s];
    float acc = __logf(Zv) + LN2 * (float)(cf[idx] + cb[idx]);
    acc = wsum(acc);
    if ((threadIdx.x & 63) == 0) atomicAdd(&out[0], acc);
}

extern "C" void kernel_launch(void* const* d_in, const int* in_sizes, int n_in,
                              void* d_out, int out_size, void* d_ws, size_t ws_size,
                              hipStream_t stream) {
    const float* logits = (const float*)d_in[0];
    const float* trans_T = (const float*)d_in[1];
    const float* trans_L = (const float*)d_in[2];
    const float* trans_R = (const float*)d_in[3];
    const int* tags = (const int*)d_in[4];
    float* out = (float*)d_out;
    float* ws = (float*)d_ws;

    hipLaunchKernelGGL(zero_out, dim3(1), dim3(64), 0, stream, out);
    hipLaunchKernelGGL(crf_T, dim3(128), dim3(64), 0, stream, logits, trans_T, ws);
    hipLaunchKernelGGL(crf_LR, dim3(4352), dim3(64), 0, stream,
                       logits, trans_T, trans_L, trans_R, tags, out);
    hipLaunchKernelGGL(t_combine, dim3(4), dim3(256), 0, stream, ws, out);
}

// Round 11
// 299.072 us; speedup vs baseline: 1.1719x; 1.1719x over previous
//
#include <hip/hip_runtime.h>

#define BB 64
#define TT 512
#define NN 48
#define PP 16

typedef float f4 __attribute__((ext_vector_type(4)));
typedef short s8v __attribute__((ext_vector_type(8)));
typedef int i4v __attribute__((ext_vector_type(4)));

#define LN2 0.6931471805599453f

__device__ __forceinline__ unsigned f2bf_bits(float x) {
    unsigned u = __builtin_bit_cast(unsigned, x);
    return (u + 0x7fffu + ((u >> 16) & 1u)) >> 16;
}
__device__ __forceinline__ int pk_bf16(float a, float b) {
    return (int)(f2bf_bits(a) | (f2bf_bits(b) << 16));
}
__device__ __forceinline__ float wsum(float v) {
#pragma unroll
    for (int k = 32; k >= 1; k >>= 1) v += __shfl_xor(v, k, 64);
    return v;
}

#define MFMA(A_, B_, C_) __builtin_amdgcn_mfma_f32_16x16x32_bf16(A_, B_, C_, 0, 0, 0)

// Opaque async load: 3x16B per lane into fixed vregs. The compiler cannot sink
// these (asm volatile) and inserts NO waitcnt for them — we control draining.
__device__ __forceinline__ void aload3(const float* q, float4& a, float4& b, float4& c) {
    asm volatile(
        "global_load_dwordx4 %0, %3, off\n\t"
        "global_load_dwordx4 %1, %3, off offset:64\n\t"
        "global_load_dwordx4 %2, %3, off offset:128"
        : "=v"(a), "=v"(b), "=v"(c)
        : "v"(q)
        : "memory");
}
// wait until at most N vector loads outstanding; block scheduler motion across.
#define WAITVM(N)                                                                   \
    do {                                                                            \
        __builtin_amdgcn_s_waitcnt((((N) & 0xF)) | ((((N) >> 4) & 0x3) << 14) |     \
                                   0x0F70);                                         \
        __builtin_amdgcn_sched_barrier(0);                                          \
    } while (0)

#define RESCALE(CNT)                                                         \
    do {                                                                     \
        float Sx = ((D0[0] + D0[1]) + (D0[2] + D0[3])) +                     \
                   ((D1[0] + D1[1]) + (D1[2] + D1[3])) +                     \
                   ((D2[0] + D2[1]) + (D2[2] + D2[3]));                      \
        Sx += __shfl_xor(Sx, 16, 64);                                        \
        Sx += __shfl_xor(Sx, 32, 64);                                        \
        int e_ = (__builtin_bit_cast(int, Sx) >> 23) - 127;                  \
        float scl_ = __builtin_bit_cast(float, (127 - e_) << 23);            \
        CNT += e_;                                                           \
        D0 *= scl_; D1 *= scl_; D2 *= scl_;                                  \
    } while (0)

#define EMMUL(E0, E1, E2)                                                    \
    do {                                                                     \
        D0[0] *= __expf(E0.x); D0[1] *= __expf(E0.y);                        \
        D0[2] *= __expf(E0.z); D0[3] *= __expf(E0.w);                        \
        D1[0] *= __expf(E1.x); D1[1] *= __expf(E1.y);                        \
        D1[2] *= __expf(E1.z); D1[3] *= __expf(E1.w);                        \
        D2[0] *= __expf(E2.x); D2[1] *= __expf(E2.y);                        \
        D2[2] *= __expf(E2.z); D2[3] *= __expf(E2.w);                        \
    } while (0)

#define REPACK_B()                                                           \
    do {                                                                     \
        i4v nb0 = {pk_bf16(D0[0], D0[1]), pk_bf16(D0[2], D0[3]),             \
                   pk_bf16(D1[0], D1[1]), pk_bf16(D1[2], D1[3])};            \
        i4v nb1 = {pk_bf16(D2[0], D2[1]), pk_bf16(D2[2], D2[3]), 0, 0};      \
        B0 = __builtin_bit_cast(s8v, nb0);                                   \
        B1 = __builtin_bit_cast(s8v, nb1);                                   \
    } while (0)

#define DO_MFMA6()                                                           \
    do {                                                                     \
        D0 = MFMA(A[0][1], B1, Z); D0 = MFMA(A[0][0], B0, D0);               \
        D1 = MFMA(A[1][1], B1, Z); D1 = MFMA(A[1][0], B0, D1);               \
        D2 = MFMA(A[2][1], B1, Z); D2 = MFMA(A[2][0], B0, D2);               \
    } while (0)

// ---------------------------------------------------------------------------
// Shared chain core. 16 seqs/wave (seq = lane&15), σ-permuted K axis so the D
// fragment repacks directly into the next B fragment. Emissions come through a
// DEPTH-deep asm-load ring (3 dwordx4/step), drained with manual vmcnt waits.
// FWD: alpha' = exp(em) ⊙ (Eᵀ alpha), rows 1..nsteps (B must be pre-inited).
// BWD: beta'  = E·(beta ⊙ exp(em)),  rows hi, hi-1, ... (nsteps rows), D=1 init.
// ---------------------------------------------------------------------------
template <int RP, int DEPTH, bool BWD>
__device__ __forceinline__ void chain(const float* __restrict__ p0, int estride,
                                      int nsteps, int hi, const s8v (&A)[3][2],
                                      s8v& B0, s8v& B1, f4& D0, f4& D1, f4& D2,
                                      int& Cexp) {
    const f4 Z = {0.f, 0.f, 0.f, 0.f};
    float4 r[DEPTH][3];
    auto issue = [&](int d, int j) {
        int rw = BWD ? (hi - (j - 1)) : j;
        if (BWD) { if (rw < 0) rw = 0; } else { if (rw > nsteps) rw = nsteps; }
        aload3(p0 + (size_t)rw * (size_t)estride, r[d][0], r[d][1], r[d][2]);
    };
#pragma unroll
    for (int d = 0; d < DEPTH; ++d) issue(d, 1 + d);

    int j = 1;
    for (;;) {
#pragma unroll
        for (int d = 0; d < DEPTH; ++d) {
            WAITVM(3 * (DEPTH - 1));  // oldest 3 loads (slot d) have landed
            float4 e0 = r[d][0], e1 = r[d][1], e2 = r[d][2];
            if (!BWD) {
                DO_MFMA6();
                EMMUL(e0, e1, e2);
                if (j == nsteps) goto done;
                if ((j & (RP - 1)) == 0) RESCALE(Cexp);
                REPACK_B();
            } else {
                EMMUL(e0, e1, e2);
                REPACK_B();
                DO_MFMA6();
                if (j == nsteps) goto done;
                if ((j & (RP - 1)) == 0) RESCALE(Cexp);
            }
            issue(d, j + DEPTH);
            ++j;
        }
    }
done:
    WAITVM(0);  // drain ring: slots' vregs may be reused by later code
}

__device__ __forceinline__ void initB(const float* __restrict__ p0, s8v& B0, s8v& B1) {
    float4 ua = *(const float4*)(p0);
    float4 ub = *(const float4*)(p0 + 16);
    float4 uc = *(const float4*)(p0 + 32);
    i4v b0i = {pk_bf16(__expf(ua.x), __expf(ua.y)), pk_bf16(__expf(ua.z), __expf(ua.w)),
               pk_bf16(__expf(ub.x), __expf(ub.y)), pk_bf16(__expf(ub.z), __expf(ub.w))};
    i4v b1i = {pk_bf16(__expf(uc.x), __expf(uc.y)), pk_bf16(__expf(uc.z), __expf(uc.w)), 0, 0};
    B0 = __builtin_bit_cast(s8v, b0i);
    B1 = __builtin_bit_cast(s8v, b1i);
}

// L/R denominator: fwd chain + final logsum.
template <int RP, int DEPTH>
__device__ __forceinline__ float den16a(const float* __restrict__ p0, int estride,
                                        int steps, const s8v (&A)[3][2]) {
    const f4 Zi = {0.f, 0.f, 0.f, 0.f};
    f4 D0 = Zi, D1 = Zi, D2 = Zi;
    s8v B0, B1;
    int Cexp = 0;
    initB(p0, B0, B1);
    chain<RP, DEPTH, false>(p0, estride, steps, 0, A, B0, B1, D0, D1, D2, Cexp);
    float S = ((D0[0] + D0[1]) + (D0[2] + D0[3])) +
              ((D1[0] + D1[1]) + (D1[2] + D1[3])) +
              ((D2[0] + D2[1]) + (D2[2] + D2[3]));
    S += __shfl_xor(S, 16, 64);
    S += __shfl_xor(S, 32, 64);
    return __logf(S) + (float)Cexp * LN2;
}

__device__ __forceinline__ float den0(const float* __restrict__ p0) {
    float4 ua = *(const float4*)(p0);
    float4 ub = *(const float4*)(p0 + 16);
    float4 uc = *(const float4*)(p0 + 32);
    float S = (__expf(ua.x) + __expf(ua.y) + __expf(ua.z) + __expf(ua.w)) +
              (__expf(ub.x) + __expf(ub.y) + __expf(ub.z) + __expf(ub.w)) +
              (__expf(uc.x) + __expf(uc.y) + __expf(uc.z) + __expf(uc.w));
    S += __shfl_xor(S, 16, 64);
    S += __shfl_xor(S, 32, 64);
    return __logf(S);
}

// A-frags fwd: A[m][k] = exp(trans[σ(k)][t*16+m])  (Eᵀ·u)
__device__ __forceinline__ void build_A_fwd(const float* __restrict__ st, s8v (&A)[3][2]) {
    int lane = threadIdx.x & 63, m = lane & 15, quad = lane >> 4;
#pragma unroll
    for (int t = 0; t < 3; ++t) {
        int col = t * 16 + m;
        i4v v0 = {pk_bf16(__expf(st[(quad * 4 + 0) * NN + col]), __expf(st[(quad * 4 + 1) * NN + col])),
                  pk_bf16(__expf(st[(quad * 4 + 2) * NN + col]), __expf(st[(quad * 4 + 3) * NN + col])),
                  pk_bf16(__expf(st[(16 + quad * 4 + 0) * NN + col]), __expf(st[(16 + quad * 4 + 1) * NN + col])),
                  pk_bf16(__expf(st[(16 + quad * 4 + 2) * NN + col]), __expf(st[(16 + quad * 4 + 3) * NN + col]))};
        i4v v1 = {pk_bf16(__expf(st[(32 + quad * 4 + 0) * NN + col]), __expf(st[(32 + quad * 4 + 1) * NN + col])),
                  pk_bf16(__expf(st[(32 + quad * 4 + 2) * NN + col]), __expf(st[(32 + quad * 4 + 3) * NN + col])),
                  0, 0};
        A[t][0] = __builtin_bit_cast(s8v, v0);
        A[t][1] = __builtin_bit_cast(s8v, v1);
    }
}

// A-frags bwd: A[m][k] = exp(trans[t*16+m][σ(k)])  (E·x)
__device__ __forceinline__ void build_A_bwd(const float* __restrict__ st, s8v (&A)[3][2]) {
    int lane = threadIdx.x & 63, m = lane & 15, quad = lane >> 4;
#pragma unroll
    for (int t = 0; t < 3; ++t) {
        const float* row = st + (t * 16 + m) * NN;
        i4v v0 = {pk_bf16(__expf(row[quad * 4 + 0]), __expf(row[quad * 4 + 1])),
                  pk_bf16(__expf(row[quad * 4 + 2]), __expf(row[quad * 4 + 3])),
                  pk_bf16(__expf(row[16 + quad * 4 + 0]), __expf(row[16 + quad * 4 + 1])),
                  pk_bf16(__expf(row[16 + quad * 4 + 2]), __expf(row[16 + quad * 4 + 3]))};
        i4v v1 = {pk_bf16(__expf(row[32 + quad * 4 + 0]), __expf(row[32 + quad * 4 + 1])),
                  pk_bf16(__expf(row[32 + quad * 4 + 2]), __expf(row[32 + quad * 4 + 3])),
                  0, 0};
        A[t][0] = __builtin_bit_cast(s8v, v0);
        A[t][1] = __builtin_bit_cast(s8v, v1);
    }
}

__device__ __forceinline__ void dumpD(float* __restrict__ dst, int* __restrict__ cdst,
                                      int g, f4 D0, f4 D1, f4 D2, int Cexp) {
    int lane = threadIdx.x & 63, seq = lane & 15, quad = lane >> 4;
    float* b = dst + (size_t)(g * 16 + seq) * 48 + quad * 4;
#pragma unroll
    for (int r = 0; r < 4; ++r) {
        b[0 * 16 + r] = D0[r];
        b[1 * 16 + r] = D1[r];
        b[2 * 16 + r] = D2[r];
    }
    if (quad == 0) cdst[g * 16 + seq] = Cexp;
}

__global__ void zero_out(float* out) {
    if (threadIdx.x < 3) out[threadIdx.x] = 0.f;
}

#define WS_BETA (64 * 16 * 48)
#define WS_C (2 * 64 * 16 * 48)

// ---------------------------------------------------------------------------
// crf_T: 128 blocks x 64 thr. bid<64: fwd half (g=bid), else bwd half.
// DEPTH=8 asm-load ring (24 KB in flight/wave) — allocator cannot sink it,
// compiler emits no extra waits; (64,1) gives a 512-VGPR budget.
// ---------------------------------------------------------------------------
__global__ __launch_bounds__(64, 1) void crf_T(const float* __restrict__ logits,
                                               const float* __restrict__ transT,
                                               float* __restrict__ ws) {
    __shared__ float st[NN * NN];
    const int tid = threadIdx.x, bid = blockIdx.x;
    for (int i = tid; i < NN * NN; i += 64) st[i] = transT[i];
    __syncthreads();

    const int lane = tid & 63, seq = lane & 15, quad = lane >> 4;
    const int dir = bid >> 6, g = bid & 63;
    const int p = g >> 2, b0 = (g & 3) * 16;
    const int steps = (TT - 1) - p;
    const int m = steps >> 1, nb = steps - m;
    const float* p0 = logits + (size_t)(p * BB + b0 + seq) * (TT * NN) + quad * 4;

    s8v A[3][2];
    const f4 Zi = {0.f, 0.f, 0.f, 0.f};
    f4 D0 = Zi, D1 = Zi, D2 = Zi;
    s8v B0, B1;
    int Cexp = 0;
    int* cf = (int*)(ws + WS_C);
    if (dir == 0) {
        build_A_fwd(st, A);
        initB(p0, B0, B1);
        chain<4, 8, false>(p0, NN, m, 0, A, B0, B1, D0, D1, D2, Cexp);
        dumpD(ws, cf, g, D0, D1, D2, Cexp);
    } else {
        build_A_bwd(st, A);
        D0 = f4{1.f, 1.f, 1.f, 1.f}; D1 = D0; D2 = D0;
        chain<4, 8, true>(p0, NN, nb, steps, A, B0, B1, D0, D1, D2, Cexp);
        dumpD(ws + WS_BETA, cf + 1024, g, D0, D1, D2, Cexp);
    }
}

// ---------------------------------------------------------------------------
// crf_LR: 4352 blocks x 64 thr (1 wave each):
//  bid<1984: L uniform (t-grouped, contiguous 3KB step chunks)
//  bid<3968: R uniform | bid<4032: L tail | bid<4096: R tail | else T-numerator
// ---------------------------------------------------------------------------
__global__ __launch_bounds__(64, 3) void crf_LR(const float* __restrict__ logits,
                                                const float* __restrict__ transT,
                                                const float* __restrict__ transL,
                                                const float* __restrict__ transR,
                                                const int* __restrict__ tags,
                                                float* __restrict__ out) {
    __shared__ float st[NN * NN];
    const int tid = threadIdx.x, bid = blockIdx.x;
    const int lane = tid & 63;
    const int quad = lane >> 4, seq = lane & 15;
    const int SPN = BB * TT * NN;

    const float* tr;
    if (bid < 1984) tr = transL;
    else if (bid < 3968) tr = transR;
    else if (bid < 4032) tr = transL;
    else if (bid < 4096) tr = transR;
    else tr = transT;
    for (int i = tid; i < NN * NN; i += 64) st[i] = tr[i];
    __syncthreads();

    float contrib = 0.f;
    int oi;
    if (bid < 3968) {
        const int isL = bid < 1984;
        const int i = isL ? bid : bid - 1984;
        const int tb = i >> 6, b = i & 63;
        const int t0 = (isL ? 0 : 16) + tb * 16;
        oi = isL ? 1 : 2;
        const int estride = isL ? SPN : SPN - NN;
        s8v A[3][2];
        build_A_fwd(st, A);
        const float* p0 = logits + (size_t)(b * TT + t0 + seq) * NN + quad * 4;
        float ld = den16a<8, 5>(p0, estride, PP - 1, A);
        int sq = lane >> 2, pc = lane & 3;
        int tq = t0 + sq;
        float sc = 0.f;
        if (isL) {
            for (int p2 = pc; p2 < PP; p2 += 4) {
                int ix = (p2 * BB + b) * TT + tq;
                int tg = tags[ix];
                sc += logits[(size_t)ix * NN + tg];
                if (p2 >= 1) sc += st[tags[ix - BB * TT] * NN + tg];
            }
        } else {
            for (int p2 = pc; p2 < PP; p2 += 4) {
                int ix = (p2 * BB + b) * TT + (tq - p2);
                int tg = tags[ix];
                sc += logits[(size_t)ix * NN + tg];
                if (p2 >= 1) sc += st[tags[ix - BB * TT + 1] * NN + tg];
            }
        }
        contrib = ((quad == 0) ? ld : 0.f) - sc;
    } else if (bid < 4096) {
        const int isL = bid < 4032;
        const int i = isL ? bid - 3968 : bid - 4032;
        const int t = isL ? 496 + (i >> 2) : (i >> 2);
        const int b0 = (i & 3) * 16;
        oi = isL ? 1 : 2;
        const int Lh = isL ? (TT - t) : (t + 1);
        const int steps = Lh - 1;
        const int estride = isL ? SPN : SPN - NN;
        s8v A[3][2];
        build_A_fwd(st, A);
        const float* p0 = logits + (size_t)(b0 + seq) * (TT * NN) + t * NN + quad * 4;
        float ld = (steps > 0) ? den16a<8, 5>(p0, estride, steps, A) : den0(p0);
        float sc = 0.f;
        int sq = lane >> 2, pc = lane & 3;
        int bq = b0 + sq;
        if (isL) {
            for (int p2 = pc; p2 < Lh; p2 += 4) {
                int ix = (p2 * BB + bq) * TT + t;
                int tg = tags[ix];
                sc += logits[(size_t)ix * NN + tg];
                if (p2 >= 1) sc += st[tags[ix - BB * TT] * NN + tg];
            }
        } else {
            for (int p2 = pc; p2 < Lh; p2 += 4) {
                int ix = (p2 * BB + bq) * TT + (t - p2);
                int tg = tags[ix];
                sc += logits[(size_t)ix * NN + tg];
                if (p2 >= 1) sc += st[tags[ix - BB * TT + 1] * NN + tg];
            }
        }
        contrib = ((quad == 0) ? ld : 0.f) - sc;
    } else {
        oi = 0;
        int q = bid - 4096;
        int g = q >> 2, phase = q & 3;
        int p = g >> 2, b0 = (g & 3) * 16;
        int Ls = TT - p;
        int sq = lane >> 2;
        int t0 = phase * 4 + (lane & 3);
        const float* lgs = logits + (size_t)(p * BB + b0 + sq) * (TT * NN);
        const int* tgs = tags + (size_t)(p * BB + b0 + sq) * TT;
        float sc = 0.f;
        for (int t = t0; t < Ls; t += 16) {
            int tg = tgs[t];
            float e = lgs[t * NN + tg];
            float tsc = (t >= 1) ? st[tgs[t - 1] * NN + tg] : 0.f;
            sc += e + tsc;
        }
        contrib = -sc;
    }

    contrib = wsum(contrib);
    if (lane == 0) atomicAdd(&out[oi], contrib);
}

// Combine T halves: out[0] += Σ_idx [ log(Σ_s alpha*beta) + ln2*(cf+cb) ]
__global__ __launch_bounds__(256) void t_combine(const float* __restrict__ ws,
                                                 float* __restrict__ out) {
    const int idx = blockIdx.x * 256 + threadIdx.x;  // 0..1023
    const float* ap = ws + (size_t)idx * 48;
    const float* bp = ws + WS_BETA + (size_t)idx * 48;
    const int* cf = (const int*)(ws + WS_C);
    const int* cb = cf + 1024;
    float Zv = 0.f;
#pragma unroll
    for (int s = 0; s < 48; ++s) Zv += ap[s] * bp[s];
    float acc = __logf(Zv) + LN2 * (float)(cf[idx] + cb[idx]);
    acc = wsum(acc);
    if ((threadIdx.x & 63) == 0) atomicAdd(&out[0], acc);
}

extern "C" void kernel_launch(void* const* d_in, const int* in_sizes, int n_in,
                              void* d_out, int out_size, void* d_ws, size_t ws_size,
                              hipStream_t stream) {
    const float* logits = (const float*)d_in[0];
    const float* trans_T = (const float*)d_in[1];
    const float* trans_L = (const float*)d_in[2];
    const float* trans_R = (const float*)d_in[3];
    const int* tags = (const int*)d_in[4];
    float* out = (float*)d_out;
    float* ws = (float*)d_ws;

    hipLaunchKernelGGL(zero_out, dim3(1), dim3(64), 0, stream, out);
    hipLaunchKernelGGL(crf_T, dim3(128), dim3(64), 0, stream, logits, trans_T, ws);
    hipLaunchKernelGGL(crf_LR, dim3(4352), dim3(64), 0, stream,
                       logits, trans_T, trans_L, trans_R, tags, out);
    hipLaunchKernelGGL(t_combine, dim3(4), dim3(256), 0, stream, ws, out);
}